// Round 1
// baseline (860.292 us; speedup 1.0000x reference)
//
#include <hip/hip_runtime.h>

// Problem constants (fixed by setup_inputs)
#define BB 8
#define CC 64
#define HH 128
#define WW 512
#define SS 512
#define HALF 256
#define HWP (HH * WW)      // 65536
#define BHW (BB * HWP)     // 524288
#define CELLS (BB * SS * SS) // 2097152

__device__ __forceinline__ unsigned int order_f32(float f) {
    unsigned int u = __float_as_uint(f);
    return (u & 0x80000000u) ? ~u : (u | 0x80000000u);
}

// Kernel 2: project pixels, atomicMin packed (y, ~idx) key per cell.
__global__ __launch_bounds__(256) void proj_kernel(
    const float* __restrict__ camera_k,
    const float* __restrict__ depth,
    const float* __restrict__ mpp_p,
    unsigned long long* __restrict__ keys)
{
    __shared__ float sk[9];
    const int idx = blockIdx.x * 256 + threadIdx.x;   // all 256 pixels of a block share one batch b
    const int b = idx >> 16;                          // HW = 65536

    if (threadIdx.x == 0) {
        // row_scale = [W/ori_grdW, H/ori_grdH, 1] = [0.5, 0.5, 1.0] (exact)
        const float rs[3] = {0.5f, 0.5f, 1.0f};
        double a[9];
        #pragma unroll
        for (int i = 0; i < 3; ++i)
            #pragma unroll
            for (int j = 0; j < 3; ++j)
                a[i*3 + j] = (double)__fmul_rn(camera_k[b*9 + i*3 + j], rs[i]);
        double det = a[0]*(a[4]*a[8]-a[5]*a[7])
                   - a[1]*(a[3]*a[8]-a[5]*a[6])
                   + a[2]*(a[3]*a[7]-a[4]*a[6]);
        double inv[9];
        inv[0] =  (a[4]*a[8]-a[5]*a[7])/det;
        inv[1] = -(a[1]*a[8]-a[2]*a[7])/det;
        inv[2] =  (a[1]*a[5]-a[2]*a[4])/det;
        inv[3] = -(a[3]*a[8]-a[5]*a[6])/det;
        inv[4] =  (a[0]*a[8]-a[2]*a[6])/det;
        inv[5] = -(a[0]*a[5]-a[2]*a[3])/det;
        inv[6] =  (a[3]*a[7]-a[4]*a[6])/det;
        inv[7] = -(a[0]*a[7]-a[1]*a[6])/det;
        inv[8] =  (a[0]*a[4]-a[1]*a[3])/det;
        #pragma unroll
        for (int i = 0; i < 9; ++i) sk[i] = (float)inv[i];
    }
    __syncthreads();

    const int rem = idx & (HWP - 1);
    const int v = rem >> 9;          // W = 512
    const int u = rem & (WW - 1);
    const float d = depth[idx];
    const float mpp = mpp_p[0];
    const float uf = (float)u, vf = (float)v;

    // Match numpy f32 semantics exactly: no FMA contraction on this chain.
    float xw = __fadd_rn(__fadd_rn(__fmul_rn(sk[0], uf), __fmul_rn(sk[1], vf)), sk[2]);
    float yw = __fadd_rn(__fadd_rn(__fmul_rn(sk[3], uf), __fmul_rn(sk[4], vf)), sk[5]);
    float zw = __fadd_rn(__fadd_rn(__fmul_rn(sk[6], uf), __fmul_rn(sk[7], vf)), sk[8]);
    float x3 = __fmul_rn(__fmul_rn(xw, d), 1.2f);
    float y3 = __fmul_rn(__fmul_rn(yw, d), 1.2f);
    float z3 = __fmul_rn(__fmul_rn(zw, d), 1.2f);

    int xi = (int)truncf(__fdiv_rn(x3, mpp));
    int zi = (int)truncf(__fdiv_rn(z3, mpp));

    if (xi >= -HALF && xi <= HALF - 1 && zi >= -HALF && zi <= HALF - 1) {
        int cell = (b << 18) | ((xi + HALF) << 9) | (zi + HALF);
        unsigned long long key =
            ((unsigned long long)order_f32(y3) << 32) | (unsigned int)(~idx);
        atomicMin(&keys[cell], key);
    }
}

// Kernel 3: one thread per cell; write all 64 channels (winner feature or 0).
// Stores are coalesced (256 consecutive zz cells per block -> 1 KiB/wave/channel).
__global__ __launch_bounds__(256) void scatter_kernel(
    const float* __restrict__ img,
    const unsigned long long* __restrict__ keys,
    float* __restrict__ out)
{
    const int cidx = blockIdx.x * 256 + threadIdx.x;
    const unsigned long long key = keys[cidx];
    const bool has = (key != ~0ull);
    const unsigned int pix = ~(unsigned int)(key & 0xFFFFFFFFull);
    const int b = cidx >> 18;
    const int rem = (int)(pix & (HWP - 1));   // v*W + u

    const float* src = img + ((size_t)b * CC) * HWP + rem;
    const size_t obase = ((size_t)b * CC) * (size_t)(SS * SS) + (size_t)(cidx & (SS * SS - 1));

    #pragma unroll 16
    for (int c = 0; c < CC; ++c) {
        float val = 0.0f;
        if (has) val = src[(size_t)c * HWP];
        out[obase + (size_t)c * (SS * SS)] = val;
    }
}

extern "C" void kernel_launch(void* const* d_in, const int* in_sizes, int n_in,
                              void* d_out, int out_size, void* d_ws, size_t ws_size,
                              hipStream_t stream) {
    const float* img      = (const float*)d_in[0];
    const float* camera_k = (const float*)d_in[1];
    const float* depth    = (const float*)d_in[2];
    const float* mpp      = (const float*)d_in[3];

    unsigned long long* keys = (unsigned long long*)d_ws;

    // Empty-cell sentinel = 0xFFFF.. (no finite y maps to it).
    hipMemsetAsync(keys, 0xFF, (size_t)CELLS * sizeof(unsigned long long), stream);

    proj_kernel<<<BHW / 256, 256, 0, stream>>>(camera_k, depth, mpp, keys);
    scatter_kernel<<<CELLS / 256, 256, 0, stream>>>(img, keys, (float*)d_out);
}

// Round 2
// 796.498 us; speedup vs baseline: 1.0801x; 1.0801x over previous
//
#include <hip/hip_runtime.h>

// Problem constants (fixed by setup_inputs)
#define BB 8
#define CC 64
#define HH 128
#define WW 512
#define SS 512
#define HALF 256
#define HWP (HH * WW)        // 65536
#define BHW (BB * HWP)       // 524288
#define CELLS (BB * SS * SS) // 2097152

__device__ __forceinline__ unsigned int order_f32(float f) {
    unsigned int u = __float_as_uint(f);
    return (u & 0x80000000u) ? ~u : (u | 0x80000000u);
}

// Kernel 2: project pixels, atomicMin packed (y, ~idx) key per cell.
__global__ __launch_bounds__(256) void proj_kernel(
    const float* __restrict__ camera_k,
    const float* __restrict__ depth,
    const float* __restrict__ mpp_p,
    unsigned long long* __restrict__ keys)
{
    __shared__ float sk[9];
    const int idx = blockIdx.x * 256 + threadIdx.x;   // all 256 pixels share one batch b
    const int b = idx >> 16;                          // HW = 65536

    if (threadIdx.x == 0) {
        const float rs[3] = {0.5f, 0.5f, 1.0f};
        double a[9];
        #pragma unroll
        for (int i = 0; i < 3; ++i)
            #pragma unroll
            for (int j = 0; j < 3; ++j)
                a[i*3 + j] = (double)__fmul_rn(camera_k[b*9 + i*3 + j], rs[i]);
        double det = a[0]*(a[4]*a[8]-a[5]*a[7])
                   - a[1]*(a[3]*a[8]-a[5]*a[6])
                   + a[2]*(a[3]*a[7]-a[4]*a[6]);
        double inv[9];
        inv[0] =  (a[4]*a[8]-a[5]*a[7])/det;
        inv[1] = -(a[1]*a[8]-a[2]*a[7])/det;
        inv[2] =  (a[1]*a[5]-a[2]*a[4])/det;
        inv[3] = -(a[3]*a[8]-a[5]*a[6])/det;
        inv[4] =  (a[0]*a[8]-a[2]*a[6])/det;
        inv[5] = -(a[0]*a[5]-a[2]*a[3])/det;
        inv[6] =  (a[3]*a[7]-a[4]*a[6])/det;
        inv[7] = -(a[0]*a[7]-a[1]*a[6])/det;
        inv[8] =  (a[0]*a[4]-a[1]*a[3])/det;
        #pragma unroll
        for (int i = 0; i < 9; ++i) sk[i] = (float)inv[i];
    }
    __syncthreads();

    const int rem = idx & (HWP - 1);
    const int v = rem >> 9;          // W = 512
    const int u = rem & (WW - 1);
    const float d = depth[idx];
    const float mpp = mpp_p[0];
    const float uf = (float)u, vf = (float)v;

    // Match numpy f32 semantics exactly: no FMA contraction on this chain.
    float xw = __fadd_rn(__fadd_rn(__fmul_rn(sk[0], uf), __fmul_rn(sk[1], vf)), sk[2]);
    float yw = __fadd_rn(__fadd_rn(__fmul_rn(sk[3], uf), __fmul_rn(sk[4], vf)), sk[5]);
    float zw = __fadd_rn(__fadd_rn(__fmul_rn(sk[6], uf), __fmul_rn(sk[7], vf)), sk[8]);
    float x3 = __fmul_rn(__fmul_rn(xw, d), 1.2f);
    float y3 = __fmul_rn(__fmul_rn(yw, d), 1.2f);
    float z3 = __fmul_rn(__fmul_rn(zw, d), 1.2f);

    int xi = (int)truncf(__fdiv_rn(x3, mpp));
    int zi = (int)truncf(__fdiv_rn(z3, mpp));

    if (xi >= -HALF && xi <= HALF - 1 && zi >= -HALF && zi <= HALF - 1) {
        int cell = (b << 18) | ((xi + HALF) << 9) | (zi + HALF);
        unsigned long long key =
            ((unsigned long long)order_f32(y3) << 32) | (unsigned int)(~idx);
        atomicMin(&keys[cell], key);
    }
}

// Kernel 3: thread = (4 consecutive zz cells) x (4 channels).
// gridDim.y splits channels so each wave's gathers hit a small set of
// L3-resident 256 KB image planes; 16 independent gathers/thread give MLP;
// stores are float4 (1 KiB/wave), perfectly coalesced.
__global__ __launch_bounds__(256) void scatter_kernel(
    const float* __restrict__ img,
    const unsigned long long* __restrict__ keys,
    float* __restrict__ out)
{
    const int q     = blockIdx.x * 256 + threadIdx.x; // cell-quad id, 0..524287
    const int c0    = blockIdx.y << 2;                // first of 4 channels
    const int cell0 = q << 2;
    const int b     = cell0 >> 18;
    const int local = cell0 & (SS * SS - 1);

    const ulonglong2* kp = (const ulonglong2*)keys + (size_t)q * 2;
    const ulonglong2 ka = kp[0];
    const ulonglong2 kb = kp[1];
    const unsigned long long k[4] = {ka.x, ka.y, kb.x, kb.y};

    int  rem[4];
    bool has[4];
    #pragma unroll
    for (int i = 0; i < 4; ++i) {
        has[i] = (k[i] != ~0ull);
        // ~key_low = pixel idx; low 16 bits = v*W+u (safe 0 if empty)
        rem[i] = (int)((~(unsigned int)(k[i] & 0xFFFFFFFFull)) & (HWP - 1));
    }

    const float* plane0 = img + ((size_t)(b * CC + c0)) * HWP;
    float*       op     = out + ((size_t)(b * CC + c0)) * (size_t)(SS * SS) + local;

    // Issue all 16 gathers first (independent -> deep MLP), then store.
    float v[4][4];
    #pragma unroll
    for (int c = 0; c < 4; ++c) {
        const float* pl = plane0 + (size_t)c * HWP;
        #pragma unroll
        for (int i = 0; i < 4; ++i)
            v[c][i] = has[i] ? pl[rem[i]] : 0.0f;
    }
    #pragma unroll
    for (int c = 0; c < 4; ++c) {
        float4 f4 = make_float4(v[c][0], v[c][1], v[c][2], v[c][3]);
        *(float4*)(op + (size_t)c * (SS * SS)) = f4;
    }
}

extern "C" void kernel_launch(void* const* d_in, const int* in_sizes, int n_in,
                              void* d_out, int out_size, void* d_ws, size_t ws_size,
                              hipStream_t stream) {
    const float* img      = (const float*)d_in[0];
    const float* camera_k = (const float*)d_in[1];
    const float* depth    = (const float*)d_in[2];
    const float* mpp      = (const float*)d_in[3];

    unsigned long long* keys = (unsigned long long*)d_ws;

    // Empty-cell sentinel = 0xFFFF.. (no finite y maps to it).
    hipMemsetAsync(keys, 0xFF, (size_t)CELLS * sizeof(unsigned long long), stream);

    proj_kernel<<<BHW / 256, 256, 0, stream>>>(camera_k, depth, mpp, keys);

    dim3 sgrid(CELLS / 4 / 256, CC / 4);
    scatter_kernel<<<sgrid, 256, 0, stream>>>(img, keys, (float*)d_out);
}

// Round 3
// 762.366 us; speedup vs baseline: 1.1285x; 1.0448x over previous
//
#include <hip/hip_runtime.h>

// Problem constants (fixed by setup_inputs)
#define BB 8
#define CC 64
#define HH 128
#define WW 512
#define SS 512
#define HALF 256
#define HWP (HH * WW)        // 65536
#define BHW (BB * HWP)       // 524288
#define CELLS (BB * SS * SS) // 2097152

__device__ __forceinline__ unsigned int order_f32(float f) {
    unsigned int u = __float_as_uint(f);
    return (u & 0x80000000u) ? ~u : (u | 0x80000000u);
}

// Kernel 2: project pixels, atomicMin packed (y, ~idx) key per cell.
__global__ __launch_bounds__(256) void proj_kernel(
    const float* __restrict__ camera_k,
    const float* __restrict__ depth,
    const float* __restrict__ mpp_p,
    unsigned long long* __restrict__ keys)
{
    __shared__ float sk[9];
    const int idx = blockIdx.x * 256 + threadIdx.x;   // all 256 pixels share one batch b
    const int b = idx >> 16;                          // HW = 65536

    if (threadIdx.x == 0) {
        const float rs[3] = {0.5f, 0.5f, 1.0f};
        double a[9];
        #pragma unroll
        for (int i = 0; i < 3; ++i)
            #pragma unroll
            for (int j = 0; j < 3; ++j)
                a[i*3 + j] = (double)__fmul_rn(camera_k[b*9 + i*3 + j], rs[i]);
        double det = a[0]*(a[4]*a[8]-a[5]*a[7])
                   - a[1]*(a[3]*a[8]-a[5]*a[6])
                   + a[2]*(a[3]*a[7]-a[4]*a[6]);
        double inv[9];
        inv[0] =  (a[4]*a[8]-a[5]*a[7])/det;
        inv[1] = -(a[1]*a[8]-a[2]*a[7])/det;
        inv[2] =  (a[1]*a[5]-a[2]*a[4])/det;
        inv[3] = -(a[3]*a[8]-a[5]*a[6])/det;
        inv[4] =  (a[0]*a[8]-a[2]*a[6])/det;
        inv[5] = -(a[0]*a[5]-a[2]*a[3])/det;
        inv[6] =  (a[3]*a[7]-a[4]*a[6])/det;
        inv[7] = -(a[0]*a[7]-a[1]*a[6])/det;
        inv[8] =  (a[0]*a[4]-a[1]*a[3])/det;
        #pragma unroll
        for (int i = 0; i < 9; ++i) sk[i] = (float)inv[i];
    }
    __syncthreads();

    const int rem = idx & (HWP - 1);
    const int v = rem >> 9;          // W = 512
    const int u = rem & (WW - 1);
    const float d = depth[idx];
    const float mpp = mpp_p[0];
    const float uf = (float)u, vf = (float)v;

    // Match numpy f32 semantics exactly: no FMA contraction on this chain.
    float xw = __fadd_rn(__fadd_rn(__fmul_rn(sk[0], uf), __fmul_rn(sk[1], vf)), sk[2]);
    float yw = __fadd_rn(__fadd_rn(__fmul_rn(sk[3], uf), __fmul_rn(sk[4], vf)), sk[5]);
    float zw = __fadd_rn(__fadd_rn(__fmul_rn(sk[6], uf), __fmul_rn(sk[7], vf)), sk[8]);
    float x3 = __fmul_rn(__fmul_rn(xw, d), 1.2f);
    float y3 = __fmul_rn(__fmul_rn(yw, d), 1.2f);
    float z3 = __fmul_rn(__fmul_rn(zw, d), 1.2f);

    int xi = (int)truncf(__fdiv_rn(x3, mpp));
    int zi = (int)truncf(__fdiv_rn(z3, mpp));

    if (xi >= -HALF && xi <= HALF - 1 && zi >= -HALF && zi <= HALF - 1) {
        int cell = (b << 18) | ((xi + HALF) << 9) | (zi + HALF);
        unsigned long long key =
            ((unsigned long long)order_f32(y3) << 32) | (unsigned int)(~idx);
        atomicMin(&keys[cell], key);
    }
}

// Kernel 3: thread = (4 consecutive zz cells) x (4 channels), with an
// XCD-locality swizzle: assuming round-robin block->XCD dispatch (n%8),
// each XCD owns 2 channel-groups and sweeps batches sequentially, so its
// active image planes (2 cgroups x 4 planes x ~1 batch = 2 MB) stay L2-
// resident and the 7x line-reuse of winner gathers is captured in-L2
// instead of re-fetched from L3. Mapping is a perf heuristic only.
__global__ __launch_bounds__(256) void scatter_kernel(
    const float* __restrict__ img,
    const unsigned long long* __restrict__ keys,
    float* __restrict__ out)
{
    const int n   = blockIdx.x;          // 0..32767
    const int xcd = n & 7;
    const int s   = n >> 3;              // 0..4095, per-XCD sequence
    const int cg  = xcd * 2 + (s & 1);   // channel group 0..15
    const int bq  = s >> 1;              // block-quad index 0..2047

    const int q     = bq * 256 + threadIdx.x; // cell-quad id, 0..524287
    const int c0    = cg << 2;                // first of 4 channels
    const int cell0 = q << 2;
    const int b     = cell0 >> 18;
    const int local = cell0 & (SS * SS - 1);

    const ulonglong2* kp = (const ulonglong2*)keys + (size_t)q * 2;
    const ulonglong2 ka = kp[0];
    const ulonglong2 kb = kp[1];
    const unsigned long long k[4] = {ka.x, ka.y, kb.x, kb.y};

    int  rem[4];
    bool has[4];
    #pragma unroll
    for (int i = 0; i < 4; ++i) {
        has[i] = (k[i] != ~0ull);
        // ~key_low = pixel idx; low 16 bits = v*W+u (safe 0 if empty)
        rem[i] = (int)((~(unsigned int)(k[i] & 0xFFFFFFFFull)) & (HWP - 1));
    }

    const float* plane0 = img + ((size_t)(b * CC + c0)) * HWP;
    float*       op     = out + ((size_t)(b * CC + c0)) * (size_t)(SS * SS) + local;

    // Issue all 16 gathers first (independent -> deep MLP), then store.
    float v[4][4];
    #pragma unroll
    for (int c = 0; c < 4; ++c) {
        const float* pl = plane0 + (size_t)c * HWP;
        #pragma unroll
        for (int i = 0; i < 4; ++i)
            v[c][i] = has[i] ? pl[rem[i]] : 0.0f;
    }
    #pragma unroll
    for (int c = 0; c < 4; ++c) {
        float4 f4 = make_float4(v[c][0], v[c][1], v[c][2], v[c][3]);
        *(float4*)(op + (size_t)c * (SS * SS)) = f4;
    }
}

extern "C" void kernel_launch(void* const* d_in, const int* in_sizes, int n_in,
                              void* d_out, int out_size, void* d_ws, size_t ws_size,
                              hipStream_t stream) {
    const float* img      = (const float*)d_in[0];
    const float* camera_k = (const float*)d_in[1];
    const float* depth    = (const float*)d_in[2];
    const float* mpp      = (const float*)d_in[3];

    unsigned long long* keys = (unsigned long long*)d_ws;

    // Empty-cell sentinel = 0xFFFF.. (no finite y maps to it).
    hipMemsetAsync(keys, 0xFF, (size_t)CELLS * sizeof(unsigned long long), stream);

    proj_kernel<<<BHW / 256, 256, 0, stream>>>(camera_k, depth, mpp, keys);

    // 8 XCD slots x (2 cgroups x 2048 quad-blocks) = 32768 blocks
    scatter_kernel<<<32768, 256, 0, stream>>>(img, keys, (float*)d_out);
}